// Round 11
// baseline (305.355 us; speedup 1.0000x reference)
//
#include <hip/hip_runtime.h>
#include <hip/hip_bf16.h>
#include <hip/hip_fp16.h>

// B=2, T=2048, C=1024, H=16, HD=64
typedef _Float16 h8 __attribute__((ext_vector_type(8)));
typedef float fx4 __attribute__((ext_vector_type(4)));

__device__ __forceinline__ void load_lds16(const void* g, void* l) {
  __builtin_amdgcn_global_load_lds((const __attribute__((address_space(1))) void*)g,
                                   (__attribute__((address_space(3))) void*)l, 16, 0, 0);
}

// ---------------- cast f32 -> f16 for x, Wq, Wk, Wv, Wp ----------------
__global__ __launch_bounds__(256) void cast_all(
    const float* __restrict__ x, const float* __restrict__ Wq,
    const float* __restrict__ Wk, const float* __restrict__ Wv,
    const float* __restrict__ Wp,
    _Float16* __restrict__ xh, _Float16* __restrict__ wqkv,
    _Float16* __restrict__ wph) {
  int g = blockIdx.x * 256 + threadIdx.x;  // units of 8 elems, total 1048576
  const float* src; _Float16* dst;
  if (g < 524288)      { size_t o = (size_t)g * 8;            src = x  + o; dst = xh + o; }
  else if (g < 655360) { size_t o = (size_t)(g - 524288) * 8; src = Wq + o; dst = wqkv + o; }
  else if (g < 786432) { size_t o = (size_t)(g - 655360) * 8; src = Wk + o; dst = wqkv + 1048576 + o; }
  else if (g < 917504) { size_t o = (size_t)(g - 786432) * 8; src = Wv + o; dst = wqkv + 2097152 + o; }
  else                 { size_t o = (size_t)(g - 917504) * 8; src = Wp + o; dst = wph + o; }
  float4 a = *(const float4*)(src);
  float4 b = *(const float4*)(src + 4);
  h8 o;
  o[0]=(_Float16)a.x; o[1]=(_Float16)a.y; o[2]=(_Float16)a.z; o[3]=(_Float16)a.w;
  o[4]=(_Float16)b.x; o[5]=(_Float16)b.y; o[6]=(_Float16)b.z; o[7]=(_Float16)b.w;
  *(h8*)dst = o;
}

// ---------------- f16 BT-GEMM: C[m,n] = sum_k A[m,k]*B[n,k] (+bias) ----------------
template<bool OUT16, bool BIAS>
__global__ __launch_bounds__(256) void gemm_bt(
    const _Float16* __restrict__ A, const _Float16* __restrict__ Bm,
    void* __restrict__ Cv, const float* __restrict__ bias,
    int M, int N, int K) {
  __shared__ _Float16 As[8192];  // [128][64] f16, rows 128B, 8 chunks of 16B, chunk^=(row&7)
  __shared__ _Float16 Bs[8192];
  const int tid  = threadIdx.x;
  const int lane = tid & 63, w = tid >> 6;
  // XCD-chunked swizzle (grid divisible by 8)
  const int chunk = (int)gridDim.x >> 3;
  const int bid = ((int)blockIdx.x & 7) * chunk + ((int)blockIdx.x >> 3);
  const int nb = N >> 7;
  const int m0 = (bid / nb) << 7;
  const int n0 = (bid % nb) << 7;
  const int wm = (w >> 1) << 6, wn = (w & 1) << 6;
  fx4 acc[4][4] = {};
  const int fbase = w * 4096 + lane * 16;

  for (int k0 = 0; k0 < K; k0 += 64) {
    __syncthreads();
#pragma unroll
    for (int q = 0; q < 4; ++q) {
      int f = fbase + q * 1024;
      int row = f >> 7;
      int sch = ((f >> 4) & 7) ^ (row & 7);
      const _Float16* gA = A  + (size_t)(m0 + row) * K + k0 + sch * 8;
      const _Float16* gB = Bm + (size_t)(n0 + row) * K + k0 + sch * 8;
      load_lds16(gA, (char*)As + w * 4096 + q * 1024);
      load_lds16(gB, (char*)Bs + w * 4096 + q * 1024);
    }
    __syncthreads();

    h8 af[4][2], bf[4][2];
#pragma unroll
    for (int s4 = 0; s4 < 4; ++s4) {
#pragma unroll
      for (int kk = 0; kk < 2; ++kk) {
        int rowa = wm + s4 * 16 + (lane & 15);
        int cha  = (kk * 4 + (lane >> 4)) ^ (rowa & 7);
        af[s4][kk] = *(const h8*)((const char*)As + rowa * 128 + cha * 16);
        int rowb = wn + s4 * 16 + (lane & 15);
        int chb  = (kk * 4 + (lane >> 4)) ^ (rowb & 7);
        bf[s4][kk] = *(const h8*)((const char*)Bs + rowb * 128 + chb * 16);
      }
    }
#pragma unroll
    for (int ms = 0; ms < 4; ++ms)
#pragma unroll
      for (int ns = 0; ns < 4; ++ns) {
        acc[ms][ns] = __builtin_amdgcn_mfma_f32_16x16x32_f16(af[ms][0], bf[ns][0], acc[ms][ns], 0, 0, 0);
        acc[ms][ns] = __builtin_amdgcn_mfma_f32_16x16x32_f16(af[ms][1], bf[ns][1], acc[ms][ns], 0, 0, 0);
      }
  }

#pragma unroll
  for (int ms = 0; ms < 4; ++ms) {
    int row0 = m0 + wm + ms * 16 + ((lane >> 4) << 2);
#pragma unroll
    for (int ns = 0; ns < 4; ++ns) {
      int col = n0 + wn + ns * 16 + (lane & 15);
      float bv = BIAS ? bias[col] : 0.0f;
#pragma unroll
      for (int e = 0; e < 4; ++e) {
        float v = acc[ms][ns][e] + bv;
        if (OUT16) ((_Float16*)Cv)[(size_t)(row0 + e) * N + col] = (_Float16)v;
        else       ((float*)Cv)[(size_t)(row0 + e) * N + col] = v;
      }
    }
  }
}

// ================= fused single-pass attention (R8 structure) =================
// Block = (bh, it): 16 key rows, ALL query cols. Logits f16 in LDS; one
// barrier; full-row nt-coalesced normalized writes. 256 threads / 4 waves,
// 2 blocks/CU. Cohorts keep uniform `it` (lockstep phases — measured best);
// LPT relabel it = 127 - s puts heavy tiles in the first cohorts so the
// drain-out tail consists of the cheapest blocks.
__global__ __launch_bounds__(256, 2) void attn_fused(
    const _Float16* __restrict__ qkv, float* __restrict__ wout,
    float* __restrict__ wdiag) {
  __shared__ _Float16 p16[16 * 2064];  // row stride 2064 f16 (4128 B)
  __shared__ float wsum[4 * 16];       // [wave][row]

  const int n = (blockIdx.x & 7) * 512 + (blockIdx.x >> 3);
  const int bh = n >> 7;
  const int it = 127 - (n & 127);      // LPT: heavy tiles dispatch first
  const int b = bh >> 4, h = bh & 15;
  const int i0 = it << 4;
  const int tid = threadIdx.x;
  const int lane = tid & 63, w = tid >> 6;
  const int lm = lane & 15, lg = lane >> 4;
  const int d0 = lg << 3;

  const _Float16* kbase = qkv + (size_t)b * 2048 * 3072 + 1024 + h * 64;
  const _Float16* qbase = qkv + (size_t)b * 2048 * 3072 + h * 64;

  // K fragment (rows i0..i0+15) — same for all waves
  h8 kf0 = *(const h8*)(kbase + (size_t)(i0 + lm) * 3072 + d0);
  h8 kf1 = *(const h8*)(kbase + (size_t)(i0 + lm) * 3072 + 32 + d0);

  const float slope = exp2f(-0.5f * (float)h);

  float psum[4] = {0.f, 0.f, 0.f, 0.f};

  for (int jt = w; jt <= it; jt += 4) {
    const int j = (jt << 4) + lm;
    h8 qf0 = *(const h8*)(qbase + (size_t)j * 3072 + d0);
    h8 qf1 = *(const h8*)(qbase + (size_t)j * 3072 + 32 + d0);
    fx4 acc = {0.f, 0.f, 0.f, 0.f};
    acc = __builtin_amdgcn_mfma_f32_16x16x32_f16(kf0, qf0, acc, 0, 0, 0);
    acc = __builtin_amdgcn_mfma_f32_16x16x32_f16(kf1, qf1, acc, 0, 0, 0);
    const bool diag = (jt == it);
#pragma unroll
    for (int e = 0; e < 4; ++e) {
      const int il = (lg << 2) + e;
      const int i = i0 + il;
      const bool live = (!diag || j <= i);
      float l = acc[e] - slope * (float)(i - j);
      if (live) psum[e] += __expf(l);
      p16[il * 2064 + j] = (_Float16)(live ? l : -60000.f);
    }
  }
#pragma unroll
  for (int e = 0; e < 4; ++e) {
    float v = psum[e];
    v += __shfl_xor(v, 1);
    v += __shfl_xor(v, 2);
    v += __shfl_xor(v, 4);
    v += __shfl_xor(v, 8);
    if (lm == 0) wsum[w * 16 + (lg << 2) + e] = v;
  }
  __syncthreads();

  float* wrow = wout + (size_t)bh * 4194304;
  float* wd = wdiag + bh * 2048;
#pragma unroll
  for (int q = 0; q < 4; ++q) {
    const int r = (w << 2) + q;
    const int i = i0 + r;
    const float rv = 1.0f / (wsum[r] + wsum[16 + r] + wsum[32 + r] + wsum[48 + r]);
    float* obase = wrow + (size_t)i * 2048;
#pragma unroll
    for (int c = 0; c < 4; ++c) {
      const int jb = (c << 9) + (lane << 3);
      fx4 lo = {0.f, 0.f, 0.f, 0.f}, hi = {0.f, 0.f, 0.f, 0.f};
      if (jb <= i) {
        h8 pv = *(const h8*)&p16[r * 2064 + jb];
#pragma unroll
        for (int e2 = 0; e2 < 8; ++e2) {
          float wv = (jb + e2 <= i) ? __expf((float)pv[e2]) * rv : 0.f;
          if (e2 < 4) lo[e2] = wv; else hi[e2 - 4] = wv;
          if (jb + e2 == i) wd[i] = wv;  // diagonal (static index)
        }
      }
      __builtin_nontemporal_store(lo, (fx4*)(obase + jb));
      __builtin_nontemporal_store(hi, (fx4*)(obase + jb + 4));
    }
  }
}

// ---------------- concat[b,t,h*64+d] = wdiag[b,h,t] * v[b,t,h,d] ----------------
__global__ __launch_bounds__(256) void diag_scale(
    const _Float16* __restrict__ qkv, const float* __restrict__ wdiag,
    _Float16* __restrict__ ch) {
  const int g = blockIdx.x * 256 + threadIdx.x;  // 524288 total (8 elems each)
  const int c = (g << 3) & 1023;
  const int bt = g >> 7;
  const int hh = c >> 6;
  const int b = bt >> 11, t = bt & 2047;
  const float wv = wdiag[((b << 4) + hh) * 2048 + t];
  h8 v = *(const h8*)(qkv + (size_t)bt * 3072 + 2048 + c);
  h8 o;
#pragma unroll
  for (int e = 0; e < 8; ++e) o[e] = (_Float16)(wv * (float)v[e]);
  *(h8*)(ch + (size_t)bt * 1024 + c) = o;
}

// ---------------- launch ----------------
extern "C" void kernel_launch(void* const* d_in, const int* in_sizes, int n_in,
                              void* d_out, int out_size, void* d_ws, size_t ws_size,
                              hipStream_t stream) {
  (void)in_sizes; (void)n_in; (void)out_size; (void)ws_size;
  const float* x  = (const float*)d_in[0];
  const float* Wq = (const float*)d_in[1];
  const float* Wk = (const float*)d_in[2];
  const float* Wv = (const float*)d_in[3];
  const float* Wp = (const float*)d_in[4];
  const float* bp = (const float*)d_in[5];

  char* ws = (char*)d_ws;
  _Float16* xh   = (_Float16*)(ws);                 // [4096,1024] f16   8 MB
  _Float16* wqkv = (_Float16*)(ws + 8388608);       // [3072,1024] f16   6 MB
  _Float16* wph  = (_Float16*)(ws + 14680064);      // [1024,1024] f16   2 MB
  _Float16* qkv  = (_Float16*)(ws + 16777216);      // [4096,3072] f16  24 MB
  float*    wdg  = (float*)   (ws + 41943040);      // [B,H,T] f32     256 KB
  _Float16* ch   = (_Float16*)(ws + 42467328);      // [4096,1024] f16   8 MB

  float* out  = (float*)d_out;          // [B,T,C] f32
  float* wout = out + 4194304;          // [B,H,T,T] f32

  cast_all<<<4096, 256, 0, stream>>>(x, Wq, Wk, Wv, Wp, xh, wqkv, wph);
  gemm_bt<true, false><<<32 * 24, 256, 0, stream>>>(xh, wqkv, (void*)qkv, nullptr, 4096, 3072, 1024);
  attn_fused<<<4096, 256, 0, stream>>>(qkv, wout, wdg);
  diag_scale<<<2048, 256, 0, stream>>>(qkv, wdg, ch);
  gemm_bt<false, true><<<32 * 8, 256, 0, stream>>>(ch, wph, (void*)out, bp, 4096, 1024, 1024);
}

// Round 12
// 245.580 us; speedup vs baseline: 1.2434x; 1.2434x over previous
//
#include <hip/hip_runtime.h>
#include <hip/hip_bf16.h>
#include <hip/hip_fp16.h>

// B=2, T=2048, C=1024, H=16, HD=64
typedef _Float16 h8 __attribute__((ext_vector_type(8)));
typedef float fx4 __attribute__((ext_vector_type(4)));

__device__ __forceinline__ void load_lds16(const void* g, void* l) {
  __builtin_amdgcn_global_load_lds((const __attribute__((address_space(1))) void*)g,
                                   (__attribute__((address_space(3))) void*)l, 16, 0, 0);
}

// ---------------- cast f32 -> f16 for x, Wq, Wk, Wv, Wp ----------------
__global__ __launch_bounds__(256) void cast_all(
    const float* __restrict__ x, const float* __restrict__ Wq,
    const float* __restrict__ Wk, const float* __restrict__ Wv,
    const float* __restrict__ Wp,
    _Float16* __restrict__ xh, _Float16* __restrict__ wqkv,
    _Float16* __restrict__ wph) {
  int g = blockIdx.x * 256 + threadIdx.x;  // units of 8 elems, total 1048576
  const float* src; _Float16* dst;
  if (g < 524288)      { size_t o = (size_t)g * 8;            src = x  + o; dst = xh + o; }
  else if (g < 655360) { size_t o = (size_t)(g - 524288) * 8; src = Wq + o; dst = wqkv + o; }
  else if (g < 786432) { size_t o = (size_t)(g - 655360) * 8; src = Wk + o; dst = wqkv + 1048576 + o; }
  else if (g < 917504) { size_t o = (size_t)(g - 786432) * 8; src = Wv + o; dst = wqkv + 2097152 + o; }
  else                 { size_t o = (size_t)(g - 917504) * 8; src = Wp + o; dst = wph + o; }
  float4 a = *(const float4*)(src);
  float4 b = *(const float4*)(src + 4);
  h8 o;
  o[0]=(_Float16)a.x; o[1]=(_Float16)a.y; o[2]=(_Float16)a.z; o[3]=(_Float16)a.w;
  o[4]=(_Float16)b.x; o[5]=(_Float16)b.y; o[6]=(_Float16)b.z; o[7]=(_Float16)b.w;
  *(h8*)dst = o;
}

// ---------------- f16 BT-GEMM: C[m,n] = sum_k A[m,k]*B[n,k] (+bias) ----------------
template<bool OUT16, bool BIAS>
__global__ __launch_bounds__(256) void gemm_bt(
    const _Float16* __restrict__ A, const _Float16* __restrict__ Bm,
    void* __restrict__ Cv, const float* __restrict__ bias,
    int M, int N, int K) {
  __shared__ _Float16 As[8192];  // [128][64] f16, rows 128B, 8 chunks of 16B, chunk^=(row&7)
  __shared__ _Float16 Bs[8192];
  const int tid  = threadIdx.x;
  const int lane = tid & 63, w = tid >> 6;
  // XCD-chunked swizzle (grid divisible by 8)
  const int chunk = (int)gridDim.x >> 3;
  const int bid = ((int)blockIdx.x & 7) * chunk + ((int)blockIdx.x >> 3);
  const int nb = N >> 7;
  const int m0 = (bid / nb) << 7;
  const int n0 = (bid % nb) << 7;
  const int wm = (w >> 1) << 6, wn = (w & 1) << 6;
  fx4 acc[4][4] = {};
  const int fbase = w * 4096 + lane * 16;

  for (int k0 = 0; k0 < K; k0 += 64) {
    __syncthreads();
#pragma unroll
    for (int q = 0; q < 4; ++q) {
      int f = fbase + q * 1024;
      int row = f >> 7;
      int sch = ((f >> 4) & 7) ^ (row & 7);
      const _Float16* gA = A  + (size_t)(m0 + row) * K + k0 + sch * 8;
      const _Float16* gB = Bm + (size_t)(n0 + row) * K + k0 + sch * 8;
      load_lds16(gA, (char*)As + w * 4096 + q * 1024);
      load_lds16(gB, (char*)Bs + w * 4096 + q * 1024);
    }
    __syncthreads();

    h8 af[4][2], bf[4][2];
#pragma unroll
    for (int s4 = 0; s4 < 4; ++s4) {
#pragma unroll
      for (int kk = 0; kk < 2; ++kk) {
        int rowa = wm + s4 * 16 + (lane & 15);
        int cha  = (kk * 4 + (lane >> 4)) ^ (rowa & 7);
        af[s4][kk] = *(const h8*)((const char*)As + rowa * 128 + cha * 16);
        int rowb = wn + s4 * 16 + (lane & 15);
        int chb  = (kk * 4 + (lane >> 4)) ^ (rowb & 7);
        bf[s4][kk] = *(const h8*)((const char*)Bs + rowb * 128 + chb * 16);
      }
    }
#pragma unroll
    for (int ms = 0; ms < 4; ++ms)
#pragma unroll
      for (int ns = 0; ns < 4; ++ns) {
        acc[ms][ns] = __builtin_amdgcn_mfma_f32_16x16x32_f16(af[ms][0], bf[ns][0], acc[ms][ns], 0, 0, 0);
        acc[ms][ns] = __builtin_amdgcn_mfma_f32_16x16x32_f16(af[ms][1], bf[ns][1], acc[ms][ns], 0, 0, 0);
      }
  }

#pragma unroll
  for (int ms = 0; ms < 4; ++ms) {
    int row0 = m0 + wm + ms * 16 + ((lane >> 4) << 2);
#pragma unroll
    for (int ns = 0; ns < 4; ++ns) {
      int col = n0 + wn + ns * 16 + (lane & 15);
      float bv = BIAS ? bias[col] : 0.0f;
#pragma unroll
      for (int e = 0; e < 4; ++e) {
        float v = acc[ms][ns][e] + bv;
        if (OUT16) ((_Float16*)Cv)[(size_t)(row0 + e) * N + col] = (_Float16)v;
        else       ((float*)Cv)[(size_t)(row0 + e) * N + col] = v;
      }
    }
  }
}

// ================= fused single-pass attention (R8 structure + Q prefetch) ==========
// Block = (bh, it): 16 key rows, ALL query cols. Logits f16 in LDS; one
// barrier; full-row nt-coalesced normalized writes. 256 threads / 4 waves,
// 2 blocks/CU, sequential it cohorts (measured best: R9/R10/R11 perturbations
// all regressed). NEW: register double-buffer prefetch of Q fragments —
// issue iteration t+1's loads before t's MFMA/exp/ds_write block so the
// ~200cy L2 latency hides under compute at 2 waves/SIMD.
__global__ __launch_bounds__(256, 2) void attn_fused(
    const _Float16* __restrict__ qkv, float* __restrict__ wout,
    float* __restrict__ wdiag) {
  __shared__ _Float16 p16[16 * 2064];  // row stride 2064 f16 (4128 B)
  __shared__ float wsum[4 * 16];       // [wave][row]

  const int n = (blockIdx.x & 7) * 512 + (blockIdx.x >> 3);
  const int bh = n >> 7, it = n & 127;
  const int b = bh >> 4, h = bh & 15;
  const int i0 = it << 4;
  const int tid = threadIdx.x;
  const int lane = tid & 63, w = tid >> 6;
  const int lm = lane & 15, lg = lane >> 4;
  const int d0 = lg << 3;

  const _Float16* kbase = qkv + (size_t)b * 2048 * 3072 + 1024 + h * 64;
  const _Float16* qbase = qkv + (size_t)b * 2048 * 3072 + h * 64;

  // K fragment (rows i0..i0+15) — same for all waves
  h8 kf0 = *(const h8*)(kbase + (size_t)(i0 + lm) * 3072 + d0);
  h8 kf1 = *(const h8*)(kbase + (size_t)(i0 + lm) * 3072 + 32 + d0);

  const float slope = exp2f(-0.5f * (float)h);

  float psum[4] = {0.f, 0.f, 0.f, 0.f};

  h8 qf0 = {}, qf1 = {}, nqf0 = {}, nqf1 = {};
  if (w <= it) {
    const int j = (w << 4) + lm;
    qf0 = *(const h8*)(qbase + (size_t)j * 3072 + d0);
    qf1 = *(const h8*)(qbase + (size_t)j * 3072 + 32 + d0);
  }
  for (int jt = w; jt <= it; jt += 4) {
    // prefetch next iteration's Q fragments (independent of this iteration)
    if (jt + 4 <= it) {
      const int j2 = ((jt + 4) << 4) + lm;
      nqf0 = *(const h8*)(qbase + (size_t)j2 * 3072 + d0);
      nqf1 = *(const h8*)(qbase + (size_t)j2 * 3072 + 32 + d0);
    }
    const int j = (jt << 4) + lm;
    fx4 acc = {0.f, 0.f, 0.f, 0.f};
    acc = __builtin_amdgcn_mfma_f32_16x16x32_f16(kf0, qf0, acc, 0, 0, 0);
    acc = __builtin_amdgcn_mfma_f32_16x16x32_f16(kf1, qf1, acc, 0, 0, 0);
    const bool diag = (jt == it);
#pragma unroll
    for (int e = 0; e < 4; ++e) {
      const int il = (lg << 2) + e;
      const int i = i0 + il;
      const bool live = (!diag || j <= i);
      float l = acc[e] - slope * (float)(i - j);
      if (live) psum[e] += __expf(l);
      p16[il * 2064 + j] = (_Float16)(live ? l : -60000.f);
    }
    qf0 = nqf0;
    qf1 = nqf1;
  }
#pragma unroll
  for (int e = 0; e < 4; ++e) {
    float v = psum[e];
    v += __shfl_xor(v, 1);
    v += __shfl_xor(v, 2);
    v += __shfl_xor(v, 4);
    v += __shfl_xor(v, 8);
    if (lm == 0) wsum[w * 16 + (lg << 2) + e] = v;
  }
  __syncthreads();

  float* wrow = wout + (size_t)bh * 4194304;
  float* wd = wdiag + bh * 2048;
#pragma unroll
  for (int q = 0; q < 4; ++q) {
    const int r = (w << 2) + q;
    const int i = i0 + r;
    const float rv = 1.0f / (wsum[r] + wsum[16 + r] + wsum[32 + r] + wsum[48 + r]);
    float* obase = wrow + (size_t)i * 2048;
#pragma unroll
    for (int c = 0; c < 4; ++c) {
      const int jb = (c << 9) + (lane << 3);
      fx4 lo = {0.f, 0.f, 0.f, 0.f}, hi = {0.f, 0.f, 0.f, 0.f};
      if (jb <= i) {
        h8 pv = *(const h8*)&p16[r * 2064 + jb];
#pragma unroll
        for (int e2 = 0; e2 < 8; ++e2) {
          float wv = (jb + e2 <= i) ? __expf((float)pv[e2]) * rv : 0.f;
          if (e2 < 4) lo[e2] = wv; else hi[e2 - 4] = wv;
          if (jb + e2 == i) wd[i] = wv;  // diagonal (static index)
        }
      }
      __builtin_nontemporal_store(lo, (fx4*)(obase + jb));
      __builtin_nontemporal_store(hi, (fx4*)(obase + jb + 4));
    }
  }
}

// ---------------- concat[b,t,h*64+d] = wdiag[b,h,t] * v[b,t,h,d] ----------------
__global__ __launch_bounds__(256) void diag_scale(
    const _Float16* __restrict__ qkv, const float* __restrict__ wdiag,
    _Float16* __restrict__ ch) {
  const int g = blockIdx.x * 256 + threadIdx.x;  // 524288 total (8 elems each)
  const int c = (g << 3) & 1023;
  const int bt = g >> 7;
  const int hh = c >> 6;
  const int b = bt >> 11, t = bt & 2047;
  const float wv = wdiag[((b << 4) + hh) * 2048 + t];
  h8 v = *(const h8*)(qkv + (size_t)bt * 3072 + 2048 + c);
  h8 o;
#pragma unroll
  for (int e = 0; e < 8; ++e) o[e] = (_Float16)(wv * (float)v[e]);
  *(h8*)(ch + (size_t)bt * 1024 + c) = o;
}

// ---------------- launch ----------------
extern "C" void kernel_launch(void* const* d_in, const int* in_sizes, int n_in,
                              void* d_out, int out_size, void* d_ws, size_t ws_size,
                              hipStream_t stream) {
  (void)in_sizes; (void)n_in; (void)out_size; (void)ws_size;
  const float* x  = (const float*)d_in[0];
  const float* Wq = (const float*)d_in[1];
  const float* Wk = (const float*)d_in[2];
  const float* Wv = (const float*)d_in[3];
  const float* Wp = (const float*)d_in[4];
  const float* bp = (const float*)d_in[5];

  char* ws = (char*)d_ws;
  _Float16* xh   = (_Float16*)(ws);                 // [4096,1024] f16   8 MB
  _Float16* wqkv = (_Float16*)(ws + 8388608);       // [3072,1024] f16   6 MB
  _Float16* wph  = (_Float16*)(ws + 14680064);      // [1024,1024] f16   2 MB
  _Float16* qkv  = (_Float16*)(ws + 16777216);      // [4096,3072] f16  24 MB
  float*    wdg  = (float*)   (ws + 41943040);      // [B,H,T] f32     256 KB
  _Float16* ch   = (_Float16*)(ws + 42467328);      // [4096,1024] f16   8 MB

  float* out  = (float*)d_out;          // [B,T,C] f32
  float* wout = out + 4194304;          // [B,H,T,T] f32

  cast_all<<<4096, 256, 0, stream>>>(x, Wq, Wk, Wv, Wp, xh, wqkv, wph);
  gemm_bt<true, false><<<32 * 24, 256, 0, stream>>>(xh, wqkv, (void*)qkv, nullptr, 4096, 3072, 1024);
  attn_fused<<<4096, 256, 0, stream>>>(qkv, wout, wdg);
  diag_scale<<<2048, 256, 0, stream>>>(qkv, wdg, ch);
  gemm_bt<false, true><<<32 * 8, 256, 0, stream>>>(ch, wph, (void*)out, bp, 4096, 1024, 1024);
}

// Round 13
// 188.200 us; speedup vs baseline: 1.6225x; 1.3049x over previous
//
#include <hip/hip_runtime.h>
#include <hip/hip_bf16.h>
#include <hip/hip_fp16.h>

// B=2, T=2048, C=1024, H=16, HD=64
typedef _Float16 h8 __attribute__((ext_vector_type(8)));
typedef _Float16 h4 __attribute__((ext_vector_type(4)));
typedef float fx4 __attribute__((ext_vector_type(4)));

__device__ __forceinline__ void load_lds16(const void* g, void* l) {
  __builtin_amdgcn_global_load_lds((const __attribute__((address_space(1))) void*)g,
                                   (__attribute__((address_space(3))) void*)l, 16, 0, 0);
}

// ---------------- cast f32 -> f16 for x, Wq, Wk, Wv, Wp ----------------
__global__ __launch_bounds__(256) void cast_all(
    const float* __restrict__ x, const float* __restrict__ Wq,
    const float* __restrict__ Wk, const float* __restrict__ Wv,
    const float* __restrict__ Wp,
    _Float16* __restrict__ xh, _Float16* __restrict__ wqkv,
    _Float16* __restrict__ wph) {
  int g = blockIdx.x * 256 + threadIdx.x;  // units of 8 elems, total 1048576
  const float* src; _Float16* dst;
  if (g < 524288)      { size_t o = (size_t)g * 8;            src = x  + o; dst = xh + o; }
  else if (g < 655360) { size_t o = (size_t)(g - 524288) * 8; src = Wq + o; dst = wqkv + o; }
  else if (g < 786432) { size_t o = (size_t)(g - 655360) * 8; src = Wk + o; dst = wqkv + 1048576 + o; }
  else if (g < 917504) { size_t o = (size_t)(g - 786432) * 8; src = Wv + o; dst = wqkv + 2097152 + o; }
  else                 { size_t o = (size_t)(g - 917504) * 8; src = Wp + o; dst = wph + o; }
  float4 a = *(const float4*)(src);
  float4 b = *(const float4*)(src + 4);
  h8 o;
  o[0]=(_Float16)a.x; o[1]=(_Float16)a.y; o[2]=(_Float16)a.z; o[3]=(_Float16)a.w;
  o[4]=(_Float16)b.x; o[5]=(_Float16)b.y; o[6]=(_Float16)b.z; o[7]=(_Float16)b.w;
  *(h8*)dst = o;
}

// ---------------- f16 BT-GEMM: C[m,n] = sum_k A[m,k]*B[n,k] (+bias) ----------------
template<bool OUT16, bool BIAS>
__global__ __launch_bounds__(256) void gemm_bt(
    const _Float16* __restrict__ A, const _Float16* __restrict__ Bm,
    void* __restrict__ Cv, const float* __restrict__ bias,
    int M, int N, int K) {
  __shared__ _Float16 As[8192];  // [128][64] f16, rows 128B, 8 chunks of 16B, chunk^=(row&7)
  __shared__ _Float16 Bs[8192];
  const int tid  = threadIdx.x;
  const int lane = tid & 63, w = tid >> 6;
  // XCD-chunked swizzle (grid divisible by 8)
  const int chunk = (int)gridDim.x >> 3;
  const int bid = ((int)blockIdx.x & 7) * chunk + ((int)blockIdx.x >> 3);
  const int nb = N >> 7;
  const int m0 = (bid / nb) << 7;
  const int n0 = (bid % nb) << 7;
  const int wm = (w >> 1) << 6, wn = (w & 1) << 6;
  fx4 acc[4][4] = {};
  const int fbase = w * 4096 + lane * 16;

  for (int k0 = 0; k0 < K; k0 += 64) {
    __syncthreads();
#pragma unroll
    for (int q = 0; q < 4; ++q) {
      int f = fbase + q * 1024;
      int row = f >> 7;
      int sch = ((f >> 4) & 7) ^ (row & 7);
      const _Float16* gA = A  + (size_t)(m0 + row) * K + k0 + sch * 8;
      const _Float16* gB = Bm + (size_t)(n0 + row) * K + k0 + sch * 8;
      load_lds16(gA, (char*)As + w * 4096 + q * 1024);
      load_lds16(gB, (char*)Bs + w * 4096 + q * 1024);
    }
    __syncthreads();

    h8 af[4][2], bf[4][2];
#pragma unroll
    for (int s4 = 0; s4 < 4; ++s4) {
#pragma unroll
      for (int kk = 0; kk < 2; ++kk) {
        int rowa = wm + s4 * 16 + (lane & 15);
        int cha  = (kk * 4 + (lane >> 4)) ^ (rowa & 7);
        af[s4][kk] = *(const h8*)((const char*)As + rowa * 128 + cha * 16);
        int rowb = wn + s4 * 16 + (lane & 15);
        int chb  = (kk * 4 + (lane >> 4)) ^ (rowb & 7);
        bf[s4][kk] = *(const h8*)((const char*)Bs + rowb * 128 + chb * 16);
      }
    }
#pragma unroll
    for (int ms = 0; ms < 4; ++ms)
#pragma unroll
      for (int ns = 0; ns < 4; ++ns) {
        acc[ms][ns] = __builtin_amdgcn_mfma_f32_16x16x32_f16(af[ms][0], bf[ns][0], acc[ms][ns], 0, 0, 0);
        acc[ms][ns] = __builtin_amdgcn_mfma_f32_16x16x32_f16(af[ms][1], bf[ns][1], acc[ms][ns], 0, 0, 0);
      }
  }

#pragma unroll
  for (int ms = 0; ms < 4; ++ms) {
    int row0 = m0 + wm + ms * 16 + ((lane >> 4) << 2);
#pragma unroll
    for (int ns = 0; ns < 4; ++ns) {
      int col = n0 + wn + ns * 16 + (lane & 15);
      float bv = BIAS ? bias[col] : 0.0f;
#pragma unroll
      for (int e = 0; e < 4; ++e) {
        float v = acc[ms][ns][e] + bv;
        if (OUT16) ((_Float16*)Cv)[(size_t)(row0 + e) * N + col] = (_Float16)v;
        else       ((float*)Cv)[(size_t)(row0 + e) * N + col] = v;
      }
    }
  }
}

// ================= fused single-pass attention (R8 base + contiguous stores) =========
// Block = (bh, it): 16 key rows, ALL query cols. Logits f16 in LDS; one
// barrier; phase 2 streams rows with FULLY CONTIGUOUS per-instruction stores:
// lane L writes floats [c*256 + 4L, +4) -> each 64-lane store = 1KB dense
// (was 16B @ 32B stride = half-dense, suspected 2x HBM write amplification).
__global__ __launch_bounds__(256, 2) void attn_fused(
    const _Float16* __restrict__ qkv, float* __restrict__ wout,
    float* __restrict__ wdiag) {
  __shared__ _Float16 p16[16 * 2064];  // row stride 2064 f16 (4128 B)
  __shared__ float wsum[4 * 16];       // [wave][row]

  const int n = (blockIdx.x & 7) * 512 + (blockIdx.x >> 3);
  const int bh = n >> 7, it = n & 127;
  const int b = bh >> 4, h = bh & 15;
  const int i0 = it << 4;
  const int tid = threadIdx.x;
  const int lane = tid & 63, w = tid >> 6;
  const int lm = lane & 15, lg = lane >> 4;
  const int d0 = lg << 3;

  const _Float16* kbase = qkv + (size_t)b * 2048 * 3072 + 1024 + h * 64;
  const _Float16* qbase = qkv + (size_t)b * 2048 * 3072 + h * 64;

  // K fragment (rows i0..i0+15) — same for all waves
  h8 kf0 = *(const h8*)(kbase + (size_t)(i0 + lm) * 3072 + d0);
  h8 kf1 = *(const h8*)(kbase + (size_t)(i0 + lm) * 3072 + 32 + d0);

  const float slope = exp2f(-0.5f * (float)h);

  float psum[4] = {0.f, 0.f, 0.f, 0.f};

  h8 qf0 = {}, qf1 = {}, nqf0 = {}, nqf1 = {};
  if (w <= it) {
    const int j = (w << 4) + lm;
    qf0 = *(const h8*)(qbase + (size_t)j * 3072 + d0);
    qf1 = *(const h8*)(qbase + (size_t)j * 3072 + 32 + d0);
  }
  for (int jt = w; jt <= it; jt += 4) {
    // prefetch next iteration's Q fragments (independent of this iteration)
    if (jt + 4 <= it) {
      const int j2 = ((jt + 4) << 4) + lm;
      nqf0 = *(const h8*)(qbase + (size_t)j2 * 3072 + d0);
      nqf1 = *(const h8*)(qbase + (size_t)j2 * 3072 + 32 + d0);
    }
    const int j = (jt << 4) + lm;
    fx4 acc = {0.f, 0.f, 0.f, 0.f};
    acc = __builtin_amdgcn_mfma_f32_16x16x32_f16(kf0, qf0, acc, 0, 0, 0);
    acc = __builtin_amdgcn_mfma_f32_16x16x32_f16(kf1, qf1, acc, 0, 0, 0);
    const bool diag = (jt == it);
#pragma unroll
    for (int e = 0; e < 4; ++e) {
      const int il = (lg << 2) + e;
      const int i = i0 + il;
      const bool live = (!diag || j <= i);
      float l = acc[e] - slope * (float)(i - j);
      if (live) psum[e] += __expf(l);
      p16[il * 2064 + j] = (_Float16)(live ? l : -60000.f);
    }
    qf0 = nqf0;
    qf1 = nqf1;
  }
#pragma unroll
  for (int e = 0; e < 4; ++e) {
    float v = psum[e];
    v += __shfl_xor(v, 1);
    v += __shfl_xor(v, 2);
    v += __shfl_xor(v, 4);
    v += __shfl_xor(v, 8);
    if (lm == 0) wsum[w * 16 + (lg << 2) + e] = v;
  }
  __syncthreads();

  float* wrow = wout + (size_t)bh * 4194304;
  float* wd = wdiag + bh * 2048;
  const int jl = lane << 2;  // lane*4 floats
#pragma unroll
  for (int q = 0; q < 4; ++q) {
    const int r = (w << 2) + q;
    const int i = i0 + r;
    const float rv = 1.0f / (wsum[r] + wsum[16 + r] + wsum[32 + r] + wsum[48 + r]);
    float* obase = wrow + (size_t)i * 2048;
    const _Float16* prow = &p16[r * 2064];
#pragma unroll
    for (int c = 0; c < 8; ++c) {
      const int jb = (c << 8) + jl;  // lane-contiguous: instr covers 1KB dense
      fx4 v = {0.f, 0.f, 0.f, 0.f};
      if (jb <= i) {
        h4 pv = *(const h4*)&prow[jb];
#pragma unroll
        for (int e2 = 0; e2 < 4; ++e2) {
          float wv = (jb + e2 <= i) ? __expf((float)pv[e2]) * rv : 0.f;
          v[e2] = wv;
          if (jb + e2 == i) wd[i] = wv;  // diagonal (static index)
        }
      }
      __builtin_nontemporal_store(v, (fx4*)(obase + jb));
    }
  }
}

// ---------------- concat[b,t,h*64+d] = wdiag[b,h,t] * v[b,t,h,d] ----------------
__global__ __launch_bounds__(256) void diag_scale(
    const _Float16* __restrict__ qkv, const float* __restrict__ wdiag,
    _Float16* __restrict__ ch) {
  const int g = blockIdx.x * 256 + threadIdx.x;  // 524288 total (8 elems each)
  const int c = (g << 3) & 1023;
  const int bt = g >> 7;
  const int hh = c >> 6;
  const int b = bt >> 11, t = bt & 2047;
  const float wv = wdiag[((b << 4) + hh) * 2048 + t];
  h8 v = *(const h8*)(qkv + (size_t)bt * 3072 + 2048 + c);
  h8 o;
#pragma unroll
  for (int e = 0; e < 8; ++e) o[e] = (_Float16)(wv * (float)v[e]);
  *(h8*)(ch + (size_t)bt * 1024 + c) = o;
}

// ---------------- launch ----------------
extern "C" void kernel_launch(void* const* d_in, const int* in_sizes, int n_in,
                              void* d_out, int out_size, void* d_ws, size_t ws_size,
                              hipStream_t stream) {
  (void)in_sizes; (void)n_in; (void)out_size; (void)ws_size;
  const float* x  = (const float*)d_in[0];
  const float* Wq = (const float*)d_in[1];
  const float* Wk = (const float*)d_in[2];
  const float* Wv = (const float*)d_in[3];
  const float* Wp = (const float*)d_in[4];
  const float* bp = (const float*)d_in[5];

  char* ws = (char*)d_ws;
  _Float16* xh   = (_Float16*)(ws);                 // [4096,1024] f16   8 MB
  _Float16* wqkv = (_Float16*)(ws + 8388608);       // [3072,1024] f16   6 MB
  _Float16* wph  = (_Float16*)(ws + 14680064);      // [1024,1024] f16   2 MB
  _Float16* qkv  = (_Float16*)(ws + 16777216);      // [4096,3072] f16  24 MB
  float*    wdg  = (float*)   (ws + 41943040);      // [B,H,T] f32     256 KB
  _Float16* ch   = (_Float16*)(ws + 42467328);      // [4096,1024] f16   8 MB

  float* out  = (float*)d_out;          // [B,T,C] f32
  float* wout = out + 4194304;          // [B,H,T,T] f32

  cast_all<<<4096, 256, 0, stream>>>(x, Wq, Wk, Wv, Wp, xh, wqkv, wph);
  gemm_bt<true, false><<<32 * 24, 256, 0, stream>>>(xh, wqkv, (void*)qkv, nullptr, 4096, 3072, 1024);
  attn_fused<<<4096, 256, 0, stream>>>(qkv, wout, wdg);
  diag_scale<<<2048, 256, 0, stream>>>(qkv, wdg, ch);
  gemm_bt<false, true><<<32 * 8, 256, 0, stream>>>(ch, wph, (void*)out, bp, 4096, 1024, 1024);
}